// Round 1
// baseline (653.205 us; speedup 1.0000x reference)
//
#include <hip/hip_runtime.h>

#define G 4
#define S 2048
#define D 1024
#define E 32
#define TOPK 4

// ---------------------------------------------------------------------------
// Kernel 1: gating GEMM + softmax + top-4, fused.
// Each half-wave (32 lanes) handles one token: lane = expert e.
// W rows are read coalesced (32 consecutive floats); x read as broadcast float4.
// ---------------------------------------------------------------------------
__global__ __launch_bounds__(256) void gemm_topk_kernel(
    const float* __restrict__ x, const float* __restrict__ W,
    const float* __restrict__ b,
    float* __restrict__ gate_ws, int* __restrict__ idx_ws)
{
    const int tid   = threadIdx.x;
    const int token = blockIdx.x * 8 + (tid >> 5);   // 8 tokens per 256-thread block
    const int e     = tid & 31;

    const float4* x4 = (const float4*)x;
    const long xb = (long)token * (D / 4);

    float acc = 0.f;
#pragma unroll 4
    for (int d4 = 0; d4 < D / 4; ++d4) {
        float4 xv = x4[xb + d4];
        const float* wp = W + d4 * 4 * E + e;
        acc = fmaf(xv.x, wp[0],     acc);
        acc = fmaf(xv.y, wp[E],     acc);
        acc = fmaf(xv.z, wp[2 * E], acc);
        acc = fmaf(xv.w, wp[3 * E], acc);
    }
    acc += b[e];

    // softmax across the 32 lanes of the half-wave
    float m = acc;
#pragma unroll
    for (int off = 16; off >= 1; off >>= 1)
        m = fmaxf(m, __shfl_xor(m, off, 32));
    float ex = __expf(acc - m);
    float sum = ex;
#pragma unroll
    for (int off = 16; off >= 1; off >>= 1)
        sum += __shfl_xor(sum, off, 32);
    float prob = ex / sum;

    const int g = token >> 11;        // token / S
    const int s = token & (S - 1);

    // top-4 by repeated argmax; ties -> lowest index (jax.lax.top_k semantics)
    float p = prob;
#pragma unroll
    for (int kk = 0; kk < TOPK; ++kk) {
        float v = p;
        int   vi = e;
#pragma unroll
        for (int off = 16; off >= 1; off >>= 1) {
            float ov = __shfl_xor(v, off, 32);
            int   oi = __shfl_xor(vi, off, 32);
            if (ov > v || (ov == v && oi < vi)) { v = ov; vi = oi; }
        }
        // all 32 lanes now agree on (v, vi)
        if (e == kk) {
            gate_ws[(kk * G + g) * S + s] = v;
            idx_ws [(kk * G + g) * S + s] = vi;
        }
        if (e == vi) p = -1.f;   // remove winner for next round
    }
}

// ---------------------------------------------------------------------------
// Kernel 2: positions via wave-ballot scan. One wave per (k,g) row (16 rows).
// Lane L (<32) holds the running count of expert L in register `cnt`.
// ---------------------------------------------------------------------------
__global__ __launch_bounds__(64) void positions_kernel(
    const int* __restrict__ idx_ws, int* __restrict__ pos_ws)
{
    const int row  = blockIdx.x;          // row = k*G + g, 16 rows
    const int lane = threadIdx.x;         // 0..63
    const int* idx = idx_ws + row * S;
    int* pos       = pos_ws + row * S;

    int cnt = 0;                          // count for expert == lane
    const unsigned long long lowmask = (1ull << lane) - 1ull;

    for (int c = 0; c < S / 64; ++c) {
        const int my = idx[c * 64 + lane];
        unsigned long long eqm = 0ull, mycol = 0ull;
#pragma unroll
        for (int ee = 0; ee < E; ++ee) {
            unsigned long long bal = __ballot(my == ee);
            if (my == ee)   eqm   = bal;   // lanes matching my expert
            if (lane == ee) mycol = bal;   // this lane's expert column count
        }
        const int prior = __shfl(cnt, my);          // count from previous chunks
        pos[c * 64 + lane] = prior + __popcll(eqm & lowmask) + 1;
        cnt += __popcll(mycol);
    }
}

// ---------------------------------------------------------------------------
// Kernel 3: zero-fill the whole output (the 534.8 MB cost floor).
// ---------------------------------------------------------------------------
__global__ __launch_bounds__(256) void zero_kernel(float* __restrict__ out, long n)
{
    const long n4 = n >> 2;
    float4* out4 = (float4*)out;
    long i = (long)blockIdx.x * blockDim.x + threadIdx.x;
    const long stride = (long)gridDim.x * blockDim.x;
    const float4 z = make_float4(0.f, 0.f, 0.f, 0.f);
    for (; i < n4; i += stride) out4[i] = z;
    if (blockIdx.x == 0 && threadIdx.x == 0) {
        for (long t = n4 << 2; t < n; ++t) out[t] = 0.f;   // tail (1 elem: loss)
    }
}

// ---------------------------------------------------------------------------
// Kernel 4: scatter the 32768 assignments into combine + dispatch regions.
// ---------------------------------------------------------------------------
__global__ __launch_bounds__(256) void scatter_kernel(
    const float* __restrict__ gate_ws, const int* __restrict__ idx_ws,
    const int* __restrict__ pos_ws, const int* __restrict__ cap_ptr,
    float* __restrict__ out)
{
    const int i = blockIdx.x * blockDim.x + threadIdx.x;   // 0 .. G*S*TOPK-1
    const int cap = *cap_ptr;                              // 256
    const long combine_size = (long)G * S * E * (cap - 1);

    const int row = i >> 11;        // k*G + g
    const int s   = i & (S - 1);
    const int g   = row & (G - 1);

    const int pos = pos_ws[i];
    if (pos < cap) {                // valid: pos in 1..cap-1
        const int   e    = idx_ws[i];
        const float gate = gate_ws[i];
        const long off = ((long)(g * S + s) * E + e) * (cap - 1) + (pos - 1);
        out[off] = gate;                    // combine_tensor
        out[combine_size + off] = 1.0f;     // dispatch_mask (prob > 0 always)
    }
}

// ---------------------------------------------------------------------------
extern "C" void kernel_launch(void* const* d_in, const int* in_sizes, int n_in,
                              void* d_out, int out_size, void* d_ws, size_t ws_size,
                              hipStream_t stream)
{
    const float* x   = (const float*)d_in[0];
    const float* W   = (const float*)d_in[1];
    const float* b   = (const float*)d_in[2];
    const int*   cap = (const int*)d_in[3];
    float* out = (float*)d_out;

    const int NA = G * S * TOPK;                 // 32768 assignments
    float* gate_ws = (float*)d_ws;
    int*   idx_ws  = (int*)((char*)d_ws + (size_t)NA * 4);
    int*   pos_ws  = (int*)((char*)d_ws + (size_t)NA * 8);

    zero_kernel<<<8192, 256, 0, stream>>>(out, (long)out_size);
    gemm_topk_kernel<<<(G * S) / 8, 256, 0, stream>>>(x, W, b, gate_ws, idx_ws);
    positions_kernel<<<G * TOPK, 64, 0, stream>>>(idx_ws, pos_ws);
    scatter_kernel<<<NA / 256, 256, 0, stream>>>(gate_ws, idx_ws, pos_ws, cap, out);
}

// Round 2
// 652.803 us; speedup vs baseline: 1.0006x; 1.0006x over previous
//
#include <hip/hip_runtime.h>

#define G 4
#define S 2048
#define D 1024
#define E 32
#define TOPK 4
#define NTOK (G * S)            // 8192 tokens
#define NROW (NTOK * E)         // 262144 (g,s,e) rows
#define ROWLEN 255              // floats per row (capacity-1)
#define HALF (NROW * ROWLEN)    // 66,846,720 floats per region (fits in int)

// tab[token*E + e] = { gate_bits, pos } ; pos in 1..255 means assigned, 0 = none.

// ---------------------------------------------------------------------------
// Kernel 1: gating GEMM + softmax + top-4 (half-wave per token, lane = expert)
// Also zero-inits the (token,expert) table (each token owns its 32 entries).
// ---------------------------------------------------------------------------
__global__ __launch_bounds__(256) void gemm_topk_kernel(
    const float* __restrict__ x, const float* __restrict__ W,
    const float* __restrict__ b,
    float* __restrict__ gate_ws, int* __restrict__ idx_ws,
    int2* __restrict__ tab)
{
    const int tid   = threadIdx.x;
    const int token = blockIdx.x * 8 + (tid >> 5);   // 8 tokens / 256-thread block
    const int e     = tid & 31;

    tab[token * E + e] = make_int2(0, 0);            // zero-init table entry

    const float4* x4 = (const float4*)x;
    const long xb = (long)token * (D / 4);

    float acc = 0.f;
#pragma unroll 4
    for (int d4 = 0; d4 < D / 4; ++d4) {
        float4 xv = x4[xb + d4];
        const float* wp = W + d4 * 4 * E + e;
        acc = fmaf(xv.x, wp[0],     acc);
        acc = fmaf(xv.y, wp[E],     acc);
        acc = fmaf(xv.z, wp[2 * E], acc);
        acc = fmaf(xv.w, wp[3 * E], acc);
    }
    acc += b[e];

    // softmax across the 32 lanes of the half-wave
    float m = acc;
#pragma unroll
    for (int off = 16; off >= 1; off >>= 1)
        m = fmaxf(m, __shfl_xor(m, off, 32));
    float ex = __expf(acc - m);
    float sum = ex;
#pragma unroll
    for (int off = 16; off >= 1; off >>= 1)
        sum += __shfl_xor(sum, off, 32);
    float prob = ex / sum;

    const int g = token >> 11;
    const int s = token & (S - 1);

    // top-4 by repeated argmax; ties -> lowest index (jax.lax.top_k semantics)
    float p = prob;
#pragma unroll
    for (int kk = 0; kk < TOPK; ++kk) {
        float v = p;
        int   vi = e;
#pragma unroll
        for (int off = 16; off >= 1; off >>= 1) {
            float ov = __shfl_xor(v, off, 32);
            int   oi = __shfl_xor(vi, off, 32);
            if (ov > v || (ov == v && oi < vi)) { v = ov; vi = oi; }
        }
        if (e == kk) {
            gate_ws[(kk * G + g) * S + s] = v;
            idx_ws [(kk * G + g) * S + s] = vi;
        }
        if (e == vi) p = -1.f;
    }
}

// ---------------------------------------------------------------------------
// Kernel 2: positions via wave-ballot scan; one wave per (k,g) row.
// Writes valid assignments {gate,pos} straight into the table.
// ---------------------------------------------------------------------------
__global__ __launch_bounds__(64) void positions_kernel(
    const int* __restrict__ idx_ws, const float* __restrict__ gate_ws,
    const int* __restrict__ cap_ptr, int2* __restrict__ tab)
{
    const int row  = blockIdx.x;          // row = k*G + g  (16 rows)
    const int lane = threadIdx.x;         // 0..63
    const int cap  = *cap_ptr;            // 256
    const int g    = row & (G - 1);
    const int* idx = idx_ws + row * S;
    const float* gw = gate_ws + row * S;

    int cnt = 0;                          // running count for expert == lane
    const unsigned long long lowmask = (1ull << lane) - 1ull;

    for (int c = 0; c < S / 64; ++c) {
        const int s  = c * 64 + lane;
        const int my = idx[s];
        unsigned long long eqm = 0ull, mycol = 0ull;
#pragma unroll
        for (int ee = 0; ee < E; ++ee) {
            unsigned long long bal = __ballot(my == ee);
            if (my == ee)   eqm   = bal;
            if (lane == ee) mycol = bal;
        }
        const int prior = __shfl(cnt, my);
        const int pos = prior + __popcll(eqm & lowmask) + 1;
        if (pos < cap) {
            tab[(g * S + s) * E + my] = make_int2(__float_as_int(gw[s]), pos);
        }
        cnt += __popcll(mycol);
    }
}

// ---------------------------------------------------------------------------
// Kernel 3: single-pass output writer. Each float4 of the output is computed
// from the table: row = flat/255 (compiler magic-div), compare pos.
// A float4 can straddle two rows -> consult tab[r] and tab[r+1].
// ---------------------------------------------------------------------------
__global__ __launch_bounds__(256) void write_out_kernel(
    const int2* __restrict__ tab, float* __restrict__ out, int n)
{
    const int n4 = n >> 2;                           // 33,423,360 float4s
    float4* out4 = (float4*)out;
    int i = blockIdx.x * blockDim.x + threadIdx.x;
    const int stride = gridDim.x * blockDim.x;

    for (; i < n4; i += stride) {
        const unsigned f = (unsigned)i << 2;         // flat float index < 2^27
        const int region = f >= (unsigned)HALF;      // 0=combine, 1=dispatch
        const unsigned fp = region ? f - (unsigned)HALF : f;
        const unsigned r  = fp / 255u;               // (g,s,e) row
        const int p0 = (int)(fp - r * 255u);         // 0..254 position of elem 0

        const int2 e0 = tab[r];
        const int2 e1 = tab[r + 1];                  // r+1 <= NROW (padded)

        const float g0 = region ? 1.0f : __int_as_float(e0.x);
        const float g1 = region ? 1.0f : __int_as_float(e1.x);

        // element j matches row r   iff j == e0.pos - 1 - p0
        // element j matches row r+1 iff j == e1.pos + 254 - p0   (only if wrapped)
        const int j0 = e0.y - 1 - p0;                           // e0.y==0 -> negative
        const int j1 = (e1.y > 0 && e1.y < 256) ? (e1.y + 254 - p0) : -1;

        float4 v;
        v.x = (j0 == 0) ? g0 : ((j1 == 0) ? g1 : 0.f);
        v.y = (j0 == 1) ? g0 : ((j1 == 1) ? g1 : 0.f);
        v.z = (j0 == 2) ? g0 : ((j1 == 2) ? g1 : 0.f);
        v.w = (j0 == 3) ? g0 : ((j1 == 3) ? g1 : 0.f);
        out4[i] = v;
    }
    if (blockIdx.x == 0 && threadIdx.x == 0) {
        for (int t = n4 << 2; t < n; ++t) out[t] = 0.f;   // loss scalar
    }
}

// ---------------------------------------------------------------------------
extern "C" void kernel_launch(void* const* d_in, const int* in_sizes, int n_in,
                              void* d_out, int out_size, void* d_ws, size_t ws_size,
                              hipStream_t stream)
{
    const float* x   = (const float*)d_in[0];
    const float* W   = (const float*)d_in[1];
    const float* b   = (const float*)d_in[2];
    const int*   cap = (const int*)d_in[3];
    float* out = (float*)d_out;

    const int NA = G * S * TOPK;                       // 32768 assignments
    int2*  tab     = (int2*)d_ws;                      // NROW+8 entries (pad)
    float* gate_ws = (float*)(tab + NROW + 8);
    int*   idx_ws  = (int*)(gate_ws + NA);

    gemm_topk_kernel<<<NTOK / 8, 256, 0, stream>>>(x, W, b, gate_ws, idx_ws, tab);
    positions_kernel<<<G * TOPK, 64, 0, stream>>>(idx_ws, gate_ws, cap, tab);
    write_out_kernel<<<8192, 256, 0, stream>>>(tab, out, out_size);
}